// Round 4
// baseline (474.401 us; speedup 1.0000x reference)
//
#include <hip/hip_runtime.h>
#include <cmath>
#include <cfloat>

#define BB 16
#define NN 1024
#define MM 1024
#define GG 8            // n-split for column phase (128 rows per slab, online lse)

static constexpr float TAU  = 0.05f;
static constexpr float INV_TAU = 1.0f / TAU;
static constexpr float LR   = 0.5f;
static constexpr float B1   = 0.9f;
static constexpr float B2   = 0.999f;
static constexpr float EPSA = 1e-8f;
// exp-arg clamp: expf(88) = 1.65e38 < FLT_MAX. Clamping the ARGUMENT (not the
// result) survives -ffinite-math-only: fminf(z, 88) can't be folded away,
// whereas fminf(expf(z), FLT_MAX) was legally deleted under fast-math (the
// root cause of rounds 0-2 emitting inf -> inf-inf = NaN in the harness diff).
static constexpr float EXP_CAP = 88.0f;

// ---- scratch layout: ALL inside d_out (64 MB). No d_ws usage at all. ----
// S_main at tail: 360448 floats = rows 16032..16383
//   u(16384) v(16384) mu(16384) vu(16384) mv(16384) vv(16384) pmax(131072) psum(131072)
#define SM_OFF   16416768   // 16777216 - 360448
#define OFF_U    0
#define OFF_V    16384
#define OFF_MU   32768
#define OFF_VU   49152
#define OFF_MV   65536
#define OFF_VV   81920
#define OFF_PM   98304
#define OFF_PS   229376
// S_low at head: rows 0..2 (3072 floats):
//   [0..351]      u[15][672..1023]
//   [352..1375]   v[15][0..1023]
//   [1376..1378]  u[0][0..2]
//   [1379..2402]  v[0][0..1023]

__device__ __forceinline__ float cexp(float z) {
    return expf(fminf(z, EXP_CAP));   // finite by construction, <= 1.65e38
}

// ---- zero the Adam state (u,v,mu,vu,mv,vv) in S_main ----
__global__ void init_state(float* __restrict__ sm) {
    int i = blockIdx.x * 256 + threadIdx.x;   // 384 blocks -> 98304
    sm[i] = 0.0f;
}

// ---- row phase: lse over M per (b,n) with v added, Adam update of u ----
// one wave per row; 4 waves per 256-thread block
__global__ void row_phase(const float* __restrict__ la, const float* __restrict__ log_a,
                          float* __restrict__ sm, float bc1, float bc2) {
    int lane = threadIdx.x & 63;
    int row  = (blockIdx.x << 2) + (threadIdx.x >> 6);   // b*NN + n
    int b    = row >> 10;
    const float4* Kr = (const float4*)(la + (size_t)row * MM);
    const float4* Vr = (const float4*)(sm + OFF_V + b * MM);
    float w[16];
    float mx = -INFINITY;
#pragma unroll
    for (int k = 0; k < 4; ++k) {
        float4 kk = Kr[lane + 64 * k];
        float4 vv = Vr[lane + 64 * k];
        w[4*k+0] = kk.x * INV_TAU + vv.x;
        w[4*k+1] = kk.y * INV_TAU + vv.y;
        w[4*k+2] = kk.z * INV_TAU + vv.z;
        w[4*k+3] = kk.w * INV_TAU + vv.w;
        mx = fmaxf(mx, fmaxf(fmaxf(w[4*k+0], w[4*k+1]), fmaxf(w[4*k+2], w[4*k+3])));
    }
#pragma unroll
    for (int off = 32; off > 0; off >>= 1)
        mx = fmaxf(mx, __shfl_xor(mx, off, 64));
    float s = 0.0f;
#pragma unroll
    for (int i = 0; i < 16; ++i) s += expf(w[i] - mx);   // args <= 0, safe
#pragma unroll
    for (int off = 32; off > 0; off >>= 1)
        s += __shfl_xor(s, off, 64);
    if (lane == 0) {
        float lse = mx + logf(s);                        // s >= 1, safe
        float ut  = log_a[row] - lse;
        float uo  = sm[OFF_U + row];
        float gu  = ut - uo;
        float m_  = B1 * sm[OFF_MU + row] + (1.0f - B1) * gu;
        float v_  = B2 * sm[OFF_VU + row] + (1.0f - B2) * gu * gu;
        sm[OFF_MU + row] = m_;
        sm[OFF_VU + row] = v_;
        sm[OFF_U + row]  = uo + LR * (m_ / bc1) / (sqrtf(v_ / bc2) + EPSA);
    }
}

// ---- col phase 1: online lse partial over a 128-row slab per column ----
// grid (M/256, GG, B); 4 interleaved online chains for ILP
__global__ void col_partial(const float* __restrict__ la, float* __restrict__ sm) {
    int m = blockIdx.x * 256 + threadIdx.x;
    int g = blockIdx.y;
    int b = blockIdx.z;
    const float* base = la + ((size_t)(b * NN + g * 128)) * MM + m;
    const float* ub   = sm + OFF_U + b * NN + g * 128;
    float mx[4] = {-INFINITY, -INFINITY, -INFINITY, -INFINITY};
    float s[4]  = {0.0f, 0.0f, 0.0f, 0.0f};
#pragma unroll 8
    for (int i = 0; i < 32; ++i) {
#pragma unroll
        for (int j = 0; j < 4; ++j) {
            int r = i + 32 * j;
            float w = base[(size_t)r * MM] * INV_TAU + ub[r];
            float mn = fmaxf(mx[j], w);
            s[j] = s[j] * expf(mx[j] - mn) + expf(w - mn);
            mx[j] = mn;
        }
    }
    float M0 = fmaxf(fmaxf(mx[0], mx[1]), fmaxf(mx[2], mx[3]));
    float S0 = s[0] * expf(mx[0] - M0) + s[1] * expf(mx[1] - M0)
             + s[2] * expf(mx[2] - M0) + s[3] * expf(mx[3] - M0);
    size_t idx = ((size_t)(b * GG + g)) * MM + m;
    sm[OFF_PM + idx] = M0;
    sm[OFF_PS + idx] = S0;
}

// ---- col phase 2: combine GG partials -> lse, Adam update of v ----
__global__ void col_combine(const float* __restrict__ log_b, float* __restrict__ sm,
                            float bc1, float bc2) {
    int i = blockIdx.x * 256 + threadIdx.x;   // b*MM + m
    int b = i >> 10;
    int m = i & 1023;
    float gm[GG], gs[GG];
    float mx = -INFINITY;
#pragma unroll
    for (int g = 0; g < GG; ++g) {
        size_t idx = ((size_t)(b * GG + g)) * MM + m;
        gm[g] = sm[OFF_PM + idx];
        gs[g] = sm[OFF_PS + idx];
        mx = fmaxf(mx, gm[g]);
    }
    float s = 0.0f;
#pragma unroll
    for (int g = 0; g < GG; ++g) s += gs[g] * expf(gm[g] - mx);
    float lse = mx + logf(s);
    float vt  = log_b[i] - lse;
    float vo  = sm[OFF_V + i];
    float gv  = vt - vo;
    float m_  = B1 * sm[OFF_MV + i] + (1.0f - B1) * gv;
    float v_  = B2 * sm[OFF_VV + i] + (1.0f - B2) * gv * gv;
    sm[OFF_MV + i] = m_;
    sm[OFF_VV + i] = v_;
    sm[OFF_V + i]  = vo + LR * (m_ / bc1) / (sqrtf(v_ / bc2) + EPSA);
}

// ---- stash the u/v slices needed after S_main/S_low get overwritten ----
__global__ void copy_low(float* __restrict__ out) {
    const float* sm = out + SM_OFF;
    int t = threadIdx.x;                         // 1 block, 256 threads
    for (int i = t; i < 352; i += 256)  out[i]        = sm[OFF_U + 15 * NN + 672 + i];
    for (int i = t; i < 1024; i += 256) out[352 + i]  = sm[OFF_V + 15 * MM + i];
    if (t < 3)                          out[1376 + t] = sm[OFF_U + t];
    for (int i = t; i < 1024; i += 256) out[1379 + i] = sm[OFF_V + i];
}

// ---- finalize A: rows 3..16031, reads u/v from S_main (tail, untouched) ----
__global__ void finalize_A(const float* __restrict__ la, float* __restrict__ out) {
    const float* sm = out + SM_OFF;
    size_t i4 = (size_t)blockIdx.x * 256 + threadIdx.x + 768;  // start at element 3072
    size_t e  = i4 * 4;
    int row = (int)(e >> 10);
    int b   = row >> 10;
    int m   = (int)(e & 1023);
    float uu = sm[OFF_U + row];
    float4 kk = ((const float4*)la)[i4];
    float4 vv = *(const float4*)(sm + OFF_V + b * MM + m);
    float4 o;
    o.x = cexp(kk.x * INV_TAU + uu + vv.x);
    o.y = cexp(kk.y * INV_TAU + uu + vv.y);
    o.z = cexp(kk.z * INV_TAU + uu + vv.z);
    o.w = cexp(kk.w * INV_TAU + uu + vv.w);
    ((float4*)out)[i4] = o;
}

// ---- finalize B: rows 16032..16383 (the S_main region), reads S_low stash ----
__global__ void finalize_B(const float* __restrict__ la, float* __restrict__ out) {
    size_t i4 = (size_t)blockIdx.x * 256 + threadIdx.x + (SM_OFF / 4);
    size_t e  = i4 * 4;
    int row = (int)(e >> 10);
    int n   = row & 1023;        // 672..1023, b == 15
    int m   = (int)(e & 1023);
    float uu = out[n - 672];                     // S_low: u[15][672..1023]
    float4 vv = *(const float4*)(out + 352 + m); // S_low: v[15][:]
    float4 kk = ((const float4*)la)[i4];
    float4 o;
    o.x = cexp(kk.x * INV_TAU + uu + vv.x);
    o.y = cexp(kk.y * INV_TAU + uu + vv.y);
    o.z = cexp(kk.z * INV_TAU + uu + vv.z);
    o.w = cexp(kk.w * INV_TAU + uu + vv.w);
    ((float4*)out)[i4] = o;
}

// ---- finalize C: rows 0..2 (the S_low region itself); one block, LDS-staged ----
__global__ void finalize_C(const float* __restrict__ la, float* __restrict__ out) {
    __shared__ float su[3];
    __shared__ float sv[1024];
    int t = threadIdx.x;                         // 1 block, 256 threads
    if (t < 3) su[t] = out[1376 + t];
    for (int i = t; i < 1024; i += 256) sv[i] = out[1379 + i];
    __syncthreads();
    for (int i4 = t; i4 < 768; i4 += 256) {      // 3072 elements
        int e   = i4 * 4;
        int row = e >> 10;                       // 0..2 (b=0, n=row)
        int m   = e & 1023;
        float uu = su[row];
        float4 kk = ((const float4*)la)[i4];
        float4 o;
        o.x = cexp(kk.x * INV_TAU + uu + sv[m + 0]);
        o.y = cexp(kk.y * INV_TAU + uu + sv[m + 1]);
        o.z = cexp(kk.z * INV_TAU + uu + sv[m + 2]);
        o.w = cexp(kk.w * INV_TAU + uu + sv[m + 3]);
        ((float4*)out)[i4] = o;
    }
}

extern "C" void kernel_launch(void* const* d_in, const int* in_sizes, int n_in,
                              void* d_out, int out_size, void* d_ws, size_t ws_size,
                              hipStream_t stream) {
    const float* log_alpha = (const float*)d_in[0];
    const float* log_a     = (const float*)d_in[1];
    const float* log_b     = (const float*)d_in[2];
    float* out = (float*)d_out;
    float* sm  = out + SM_OFF;

    init_state<<<384, 256, 0, stream>>>(sm);
    for (int t = 1; t <= 10; ++t) {
        float bc1 = 1.0f - powf(B1, (float)t);
        float bc2 = 1.0f - powf(B2, (float)t);
        row_phase<<<BB * NN / 4, 256, 0, stream>>>(log_alpha, log_a, sm, bc1, bc2);
        col_partial<<<dim3(MM / 256, GG, BB), 256, 0, stream>>>(log_alpha, sm);
        col_combine<<<BB * MM / 256, 256, 0, stream>>>(log_b, sm, bc1, bc2);
    }
    copy_low<<<1, 256, 0, stream>>>(out);
    finalize_A<<<16029, 256, 0, stream>>>(log_alpha, out);
    finalize_B<<<352, 256, 0, stream>>>(log_alpha, out);
    finalize_C<<<1, 256, 0, stream>>>(log_alpha, out);
}